// Round 17
// baseline (158.493 us; speedup 1.0000x reference)
//
#include <hip/hip_runtime.h>
#include <hip/hip_fp16.h>

#define D 96
#define D4 24
#define MAXBINS 256
#define CAP 16384   // slab capacity per 256-node bucket (avg fill ~4096)

static inline size_t alignup(size_t x) { return (x + 255) & ~size_t(255); }

__device__ inline float4 f4fma(float s, float4 a, float4 acc) {
    acc.x = fmaf(s, a.x, acc.x);
    acc.y = fmaf(s, a.y, acc.y);
    acc.z = fmaf(s, a.z, acc.z);
    acc.w = fmaf(s, a.w, acc.w);
    return acc;
}

// unpack 4 fp16 (uint2) and ADD into a float4 accumulator
__device__ inline void u2add(uint2 rv, float4& a) {
    __half2 h0 = *reinterpret_cast<__half2*>(&rv.x);
    __half2 h1 = *reinterpret_cast<__half2*>(&rv.y);
    float2 f0 = __half22float2(h0);
    float2 f1 = __half22float2(h1);
    a.x += f0.x; a.y += f0.y; a.z += f1.x; a.w += f1.y;
}

__device__ inline uint2 packh4(float sc, float4 v) {
    __half2 ha = __float22half2_rn(make_float2(sc * v.x, sc * v.y));
    __half2 hb = __float22half2_rn(make_float2(sc * v.z, sc * v.w));
    uint2 st;
    st.x = *reinterpret_cast<unsigned int*>(&ha);
    st.y = *reinterpret_cast<unsigned int*>(&hb);
    return st;
}

// cursor[b] = b*CAP  (slab base per bucket)
__global__ __launch_bounds__(256) void init_kernel(int* __restrict__ cursor) {
    cursor[threadIdx.x] = (int)threadIdx.x * CAP;
}

// 196 blocks x 4096 edges: LDS histogram -> one global ticket per (block,bucket)
// -> ranked write of packed (d8<<16|src) into the bucket slab.
__global__ __launch_bounds__(1024) void dist_kernel(const int* __restrict__ src,
                                                    const int* __restrict__ dst, int E,
                                                    int* __restrict__ cursor,
                                                    int* __restrict__ ebuf) {
    __shared__ int h[MAXBINS];
    __shared__ int base[MAXBINS];
    const int tid = threadIdx.x;
    if (tid < MAXBINS) h[tid] = 0;
    __syncthreads();
    const int e0 = blockIdx.x * 4096 + tid;
    int pk[4], bn[4], rk[4];
    bool val[4];
    #pragma unroll
    for (int q = 0; q < 4; ++q) {
        int e = e0 + q * 1024;
        val[q] = e < E;
        if (val[q]) {
            int s = src[e], d = dst[e];
            bn[q] = d >> 8;
            pk[q] = ((d & 255) << 16) | s;      // src < 65536
            rk[q] = atomicAdd(&h[bn[q]], 1);
        }
    }
    __syncthreads();
    if (tid < MAXBINS && h[tid]) base[tid] = atomicAdd(&cursor[tid], h[tid]);
    __syncthreads();
    #pragma unroll
    for (int q = 0; q < 4; ++q)
        if (val[q]) ebuf[base[bn[q]] + rk[q]] = pk[q];
}

// One workgroup per bucket. Pass 1: per-node counts + prefix -> dinv, rowspan
// (slab-indexed). Pass 2: rank edges, write src-only CSR into the slab region.
__global__ __launch_bounds__(256) void bucketAB_kernel(const int* __restrict__ ebuf,
                                                       const int* __restrict__ cursor,
                                                       float* __restrict__ dinv,
                                                       int2* __restrict__ rowspan,
                                                       int* __restrict__ csr, int n) {
    __shared__ int cnt[256];
    __shared__ int cur[256];
    __shared__ int wsum[4];
    const int k = blockIdx.x;
    const int tid = threadIdx.x;
    const int bstart = k * CAP;
    const int bend = cursor[k];
    cnt[tid] = 0;
    __syncthreads();
    for (int e = bstart + tid; e < bend; e += 256)
        atomicAdd(&cnt[(ebuf[e] >> 16) & 255], 1);
    __syncthreads();
    int v = cnt[tid];
    const int lane = tid & 63, wid = tid >> 6;
    int sc = v;
    #pragma unroll
    for (int off = 1; off < 64; off <<= 1) {
        int t = __shfl_up(sc, off);
        if (lane >= off) sc += t;
    }
    if (lane == 63) wsum[wid] = sc;
    __syncthreads();
    int wprefix = 0;
    #pragma unroll
    for (int w = 0; w < 4; ++w)
        if (w < wid) wprefix += wsum[w];
    int mybase = bstart + wprefix + (sc - v);
    int node = k * 256 + tid;
    if (node < n) {
        dinv[node] = rsqrtf((float)(v + 1));       // +1 = self-loop
        rowspan[node] = make_int2(mybase, mybase + v);
    }
    cur[tid] = mybase;
    __syncthreads();
    for (int e = bstart + tid; e < bend; e += 256) {
        int pe = ebuf[e];
        int pos = atomicAdd(&cur[(pe >> 16) & 255], 1);
        csr[pos] = pe & 0xFFFF;
    }
}

// ---- dense transform + aggregation ----

// Y[n,96](fp16, pre-scaled by dinv[row]) = X[n,96](fp32) @ W[96,96](fp32).
__global__ __launch_bounds__(192) void matmul_kernel(const float* __restrict__ X,
                                                     const float* __restrict__ W,
                                                     const float* __restrict__ dinv,
                                                     uint2* __restrict__ Y, int n) {
    __shared__ float XsT[96 * 64];
    const int t = threadIdx.x;        // 0..23 col-group
    const int y = threadIdx.y;        // 0..7 row-group
    const int tid = y * 24 + t;
    const int row0 = blockIdx.x * 64;
    const float4* X4 = (const float4*)X;

    for (int i = tid; i < 64 * 24; i += 192) {
        int r = i / 24, c4 = i % 24;
        float4 v = make_float4(0.f, 0.f, 0.f, 0.f);
        if (row0 + r < n) v = X4[(size_t)(row0 + r) * D4 + c4];
        int rs = r ^ ((c4 & 15) << 2);
        XsT[(c4 * 4 + 0) * 64 + rs] = v.x;
        XsT[(c4 * 4 + 1) * 64 + rs] = v.y;
        XsT[(c4 * 4 + 2) * 64 + rs] = v.z;
        XsT[(c4 * 4 + 3) * 64 + rs] = v.w;
    }
    __syncthreads();

    const float4* W4 = (const float4*)W;
    float4 acc[8];
    #pragma unroll
    for (int r = 0; r < 8; ++r) acc[r] = make_float4(0.f, 0.f, 0.f, 0.f);
    const int rbase = y * 8;

    #pragma unroll 8
    for (int k = 0; k < 96; ++k) {
        float4 w = W4[k * D4 + t];
        int base0 = (rbase ^ (((k >> 2) & 15) << 2));
        float4 xa = *(const float4*)&XsT[k * 64 + base0];
        float4 xb = *(const float4*)&XsT[k * 64 + (base0 ^ 4)];
        acc[0] = f4fma(xa.x, w, acc[0]);
        acc[1] = f4fma(xa.y, w, acc[1]);
        acc[2] = f4fma(xa.z, w, acc[2]);
        acc[3] = f4fma(xa.w, w, acc[3]);
        acc[4] = f4fma(xb.x, w, acc[4]);
        acc[5] = f4fma(xb.y, w, acc[5]);
        acc[6] = f4fma(xb.z, w, acc[6]);
        acc[7] = f4fma(xb.w, w, acc[7]);
    }

    #pragma unroll
    for (int r = 0; r < 8; ++r) {
        int row = row0 + rbase + r;
        if (row < n) Y[(size_t)row * D4 + t] = packh4(dinv[row], acc[r]);
    }
}

// per-node gather-aggregate body: a = sum_e XWS[src_e,:] + XWS[i,:]
__device__ inline float4 gather_row(const uint2* __restrict__ XH,
                                    const int* __restrict__ csr,
                                    int2 be, int i, int t) {
    float4 a = make_float4(0.f, 0.f, 0.f, 0.f);
    int p = be.x;
    const int end = be.y;
    for (; p + 8 <= end; p += 8) {
        int s0 = csr[p + 0];
        int s1 = csr[p + 1];
        int s2 = csr[p + 2];
        int s3 = csr[p + 3];
        int s4 = csr[p + 4];
        int s5 = csr[p + 5];
        int s6 = csr[p + 6];
        int s7 = csr[p + 7];
        uint2 r0 = XH[(size_t)s0 * D4 + t];
        uint2 r1 = XH[(size_t)s1 * D4 + t];
        uint2 r2 = XH[(size_t)s2 * D4 + t];
        uint2 r3 = XH[(size_t)s3 * D4 + t];
        uint2 r4 = XH[(size_t)s4 * D4 + t];
        uint2 r5 = XH[(size_t)s5 * D4 + t];
        uint2 r6 = XH[(size_t)s6 * D4 + t];
        uint2 r7 = XH[(size_t)s7 * D4 + t];
        u2add(r0, a); u2add(r1, a); u2add(r2, a); u2add(r3, a);
        u2add(r4, a); u2add(r5, a); u2add(r6, a); u2add(r7, a);
    }
    if (p + 4 <= end) {
        int s0 = csr[p + 0];
        int s1 = csr[p + 1];
        int s2 = csr[p + 2];
        int s3 = csr[p + 3];
        uint2 r0 = XH[(size_t)s0 * D4 + t];
        uint2 r1 = XH[(size_t)s1 * D4 + t];
        uint2 r2 = XH[(size_t)s2 * D4 + t];
        uint2 r3 = XH[(size_t)s3 * D4 + t];
        u2add(r0, a); u2add(r1, a); u2add(r2, a); u2add(r3, a);
        p += 4;
    }
    for (; p < end; ++p)
        u2add(XH[(size_t)csr[p] * D4 + t], a);
    u2add(XH[(size_t)i * D4 + t], a);   // self term (pre-scaled row)
    return a;
}

// FUSED layer-1 aggregate + layer-2 transform (v2):
// h[i,:] = prelu(dinv[i]*gather + b1) kept in LDS (6.4 KB, stride 100 = no
// bank conflicts); W2 streamed from global (L2-resident broadcast, no LDS stage).
// xw2[i,:] = fp16( dinv[i] * (h[i,:] @ W2) ). block (24,16).
__global__ __launch_bounds__(384) void agg_mm_kernel(const uint2* __restrict__ XH,
                                                     const int* __restrict__ csr,
                                                     const int2* __restrict__ rowspan,
                                                     const float* __restrict__ dinv,
                                                     const float4* __restrict__ b4,
                                                     const float4* __restrict__ pa4,
                                                     const float* __restrict__ W2,
                                                     uint2* __restrict__ Y, int n) {
    __shared__ float hbuf[16][100];     // stride 100: 100%32=4 -> 2-way max (free)
    const int t = threadIdx.x;          // 0..23
    const int y = threadIdx.y;          // 0..15
    const int i = blockIdx.x * 16 + y;
    const bool live = i < n;

    float di = 1.f;
    if (live) {
        di = dinv[i];
        float4 a = gather_row(XH, csr, rowspan[i], i, t);
        float4 b = b4[t], q = pa4[t];
        float4 v;
        v.x = fmaf(di, a.x, b.x);
        v.y = fmaf(di, a.y, b.y);
        v.z = fmaf(di, a.z, b.z);
        v.w = fmaf(di, a.w, b.w);
        v.x = v.x > 0.f ? v.x : q.x * v.x;
        v.y = v.y > 0.f ? v.y : q.y * v.y;
        v.z = v.z > 0.f ? v.z : q.z * v.z;
        v.w = v.w > 0.f ? v.w : q.w * v.w;
        *(float4*)&hbuf[y][4 * t] = v;
    }
    __syncthreads();

    // h[y,:] @ W2 -> cols 4t..4t+3 ; W2 rows streamed from global (broadcast)
    const float4* W24 = (const float4*)W2;
    float4 acc = make_float4(0.f, 0.f, 0.f, 0.f);
    #pragma unroll 8
    for (int k = 0; k < 96; ++k)
        acc = f4fma(hbuf[y][k], W24[k * D4 + t], acc);

    if (live) Y[(size_t)i * D4 + t] = packh4(di, acc);
}

// final aggregate: out[i,:] = prelu( dinv[i]*( sum_e XWS2[src_e,:] + XWS2[i,:] ) + b2 )
__global__ __launch_bounds__(384) void aggregate_kernel(const uint2* __restrict__ XH,
                                                        const int* __restrict__ csr,
                                                        const int2* __restrict__ rowspan,
                                                        const float* __restrict__ dinv,
                                                        const float4* __restrict__ b4,
                                                        const float4* __restrict__ pa4,
                                                        float4* __restrict__ out4, int n) {
    const int i = blockIdx.x * 16 + threadIdx.y;
    const int t = threadIdx.x;  // 0..23
    if (i >= n) return;
    float4 a = gather_row(XH, csr, rowspan[i], i, t);
    const float di = dinv[i];
    float4 b = b4[t], q = pa4[t];
    float4 v;
    v.x = fmaf(di, a.x, b.x);
    v.y = fmaf(di, a.y, b.y);
    v.z = fmaf(di, a.z, b.z);
    v.w = fmaf(di, a.w, b.w);
    v.x = v.x > 0.f ? v.x : q.x * v.x;
    v.y = v.y > 0.f ? v.y : q.y * v.y;
    v.z = v.z > 0.f ? v.z : q.z * v.z;
    v.w = v.w > 0.f ? v.w : q.w * v.w;
    out4[(size_t)i * D4 + t] = v;
}

extern "C" void kernel_launch(void* const* d_in, const int* in_sizes, int n_in,
                              void* d_out, int out_size, void* d_ws, size_t ws_size,
                              hipStream_t stream) {
    const float* x   = (const float*)d_in[0];
    const int*   ei  = (const int*)d_in[1];
    const float* W1  = (const float*)d_in[2];
    const float* b1  = (const float*)d_in[3];
    const float* W2  = (const float*)d_in[4];
    const float* b2  = (const float*)d_in[5];
    const float* pa  = (const float*)d_in[6];
    const int n = in_sizes[0] / D;
    const int E = in_sizes[1] / 2;
    const int* srcp = ei;
    const int* dstp = ei + E;

    const int nbins = (n + 255) / 256;               // 196
    const int nblk  = (E + 4095) / 4096;             // 196

    char* w = (char*)d_ws;
    int*   cursor  = (int*)w;    w += alignup(256 * 4);
    int*   ebuf    = (int*)w;    w += alignup((size_t)nbins * CAP * 4);
    int*   csr     = (int*)w;    w += alignup((size_t)nbins * CAP * 4);
    float* dinv    = (float*)w;  w += alignup((size_t)n * 4);
    int2*  rowspan = (int2*)w;   w += alignup((size_t)n * 8);
    uint2* xw      = (uint2*)w;  w += alignup((size_t)n * D * 2);  // fp16 pre-scaled
    uint2* xw2     = (uint2*)w;  w += alignup((size_t)n * D * 2);  // fp16 pre-scaled (layer 2)
    float* out     = (float*)d_out;

    init_kernel<<<1, 256, 0, stream>>>(cursor);
    dist_kernel<<<nblk, 1024, 0, stream>>>(srcp, dstp, E, cursor, ebuf);
    bucketAB_kernel<<<nbins, 256, 0, stream>>>(ebuf, cursor, dinv, rowspan, csr, n);

    dim3 mblk(24, 8);
    const int mgrid = (n + 63) / 64;
    dim3 ablk(24, 16);
    const int agrid = (n + 15) / 16;

    matmul_kernel<<<mgrid, mblk, 0, stream>>>(x, W1, dinv, xw, n);
    agg_mm_kernel<<<agrid, ablk, 0, stream>>>(xw, csr, rowspan, dinv,
                                              (const float4*)b1, (const float4*)pa,
                                              W2, xw2, n);
    aggregate_kernel<<<agrid, ablk, 0, stream>>>(xw2, csr, rowspan, dinv,
                                                 (const float4*)b2, (const float4*)pa,
                                                 (float4*)out, n);
}

// Round 18
// 135.799 us; speedup vs baseline: 1.1671x; 1.1671x over previous
//
#include <hip/hip_runtime.h>
#include <hip/hip_fp16.h>

#define D 96
#define D4 24
#define MAXBINS 256
#define CAP 16384   // slab capacity per 256-node bucket (avg fill ~4096)

static inline size_t alignup(size_t x) { return (x + 255) & ~size_t(255); }

__device__ inline float4 f4fma(float s, float4 a, float4 acc) {
    acc.x = fmaf(s, a.x, acc.x);
    acc.y = fmaf(s, a.y, acc.y);
    acc.z = fmaf(s, a.z, acc.z);
    acc.w = fmaf(s, a.w, acc.w);
    return acc;
}

// unpack 4 fp16 (uint2) and ADD into a float4 accumulator
__device__ inline void u2add(uint2 rv, float4& a) {
    __half2 h0 = *reinterpret_cast<__half2*>(&rv.x);
    __half2 h1 = *reinterpret_cast<__half2*>(&rv.y);
    float2 f0 = __half22float2(h0);
    float2 f1 = __half22float2(h1);
    a.x += f0.x; a.y += f0.y; a.z += f1.x; a.w += f1.y;
}

// cursor[b] = b*CAP  (slab base per bucket)
__global__ __launch_bounds__(256) void init_kernel(int* __restrict__ cursor) {
    cursor[threadIdx.x] = (int)threadIdx.x * CAP;
}

// 196 blocks x 4096 edges: LDS histogram -> one global ticket per (block,bucket)
// -> ranked write of packed (d8<<16|src) into the bucket slab.
__global__ __launch_bounds__(1024) void dist_kernel(const int* __restrict__ src,
                                                    const int* __restrict__ dst, int E,
                                                    int* __restrict__ cursor,
                                                    int* __restrict__ ebuf) {
    __shared__ int h[MAXBINS];
    __shared__ int base[MAXBINS];
    const int tid = threadIdx.x;
    if (tid < MAXBINS) h[tid] = 0;
    __syncthreads();
    const int e0 = blockIdx.x * 4096 + tid;
    int pk[4], bn[4], rk[4];
    bool val[4];
    #pragma unroll
    for (int q = 0; q < 4; ++q) {
        int e = e0 + q * 1024;
        val[q] = e < E;
        if (val[q]) {
            int s = src[e], d = dst[e];
            bn[q] = d >> 8;
            pk[q] = ((d & 255) << 16) | s;      // src < 65536
            rk[q] = atomicAdd(&h[bn[q]], 1);
        }
    }
    __syncthreads();
    if (tid < MAXBINS && h[tid]) base[tid] = atomicAdd(&cursor[tid], h[tid]);
    __syncthreads();
    #pragma unroll
    for (int q = 0; q < 4; ++q)
        if (val[q]) ebuf[base[bn[q]] + rk[q]] = pk[q];
}

// One workgroup per bucket. Pass 1: per-node counts + prefix -> dinv, rowspan
// (slab-indexed). Pass 2: rank edges, write src-only CSR into the slab region.
__global__ __launch_bounds__(256) void bucketAB_kernel(const int* __restrict__ ebuf,
                                                       const int* __restrict__ cursor,
                                                       float* __restrict__ dinv,
                                                       int2* __restrict__ rowspan,
                                                       int* __restrict__ csr, int n) {
    __shared__ int cnt[256];
    __shared__ int cur[256];
    __shared__ int wsum[4];
    const int k = blockIdx.x;
    const int tid = threadIdx.x;
    const int bstart = k * CAP;
    const int bend = cursor[k];
    cnt[tid] = 0;
    __syncthreads();
    for (int e = bstart + tid; e < bend; e += 256)
        atomicAdd(&cnt[(ebuf[e] >> 16) & 255], 1);
    __syncthreads();
    int v = cnt[tid];
    const int lane = tid & 63, wid = tid >> 6;
    int sc = v;
    #pragma unroll
    for (int off = 1; off < 64; off <<= 1) {
        int t = __shfl_up(sc, off);
        if (lane >= off) sc += t;
    }
    if (lane == 63) wsum[wid] = sc;
    __syncthreads();
    int wprefix = 0;
    #pragma unroll
    for (int w = 0; w < 4; ++w)
        if (w < wid) wprefix += wsum[w];
    int mybase = bstart + wprefix + (sc - v);
    int node = k * 256 + tid;
    if (node < n) {
        dinv[node] = rsqrtf((float)(v + 1));       // +1 = self-loop
        rowspan[node] = make_int2(mybase, mybase + v);
    }
    cur[tid] = mybase;
    __syncthreads();
    for (int e = bstart + tid; e < bend; e += 256) {
        int pe = ebuf[e];
        int pos = atomicAdd(&cur[(pe >> 16) & 255], 1);
        csr[pos] = pe & 0xFFFF;
    }
}

// ---- dense transform + aggregation ----

// Y[n,96](fp16, pre-scaled by dinv[row]) = X[n,96](fp32) @ W[96,96](fp32).
__global__ __launch_bounds__(192) void matmul_kernel(const float* __restrict__ X,
                                                     const float* __restrict__ W,
                                                     const float* __restrict__ dinv,
                                                     uint2* __restrict__ Y, int n) {
    __shared__ float XsT[96 * 64];
    const int t = threadIdx.x;        // 0..23 col-group
    const int y = threadIdx.y;        // 0..7 row-group
    const int tid = y * 24 + t;
    const int row0 = blockIdx.x * 64;
    const float4* X4 = (const float4*)X;

    for (int i = tid; i < 64 * 24; i += 192) {
        int r = i / 24, c4 = i % 24;
        float4 v = make_float4(0.f, 0.f, 0.f, 0.f);
        if (row0 + r < n) v = X4[(size_t)(row0 + r) * D4 + c4];
        int rs = r ^ ((c4 & 15) << 2);
        XsT[(c4 * 4 + 0) * 64 + rs] = v.x;
        XsT[(c4 * 4 + 1) * 64 + rs] = v.y;
        XsT[(c4 * 4 + 2) * 64 + rs] = v.z;
        XsT[(c4 * 4 + 3) * 64 + rs] = v.w;
    }
    __syncthreads();

    const float4* W4 = (const float4*)W;
    float4 acc[8];
    #pragma unroll
    for (int r = 0; r < 8; ++r) acc[r] = make_float4(0.f, 0.f, 0.f, 0.f);
    const int rbase = y * 8;

    #pragma unroll 8
    for (int k = 0; k < 96; ++k) {
        float4 w = W4[k * D4 + t];
        int base0 = (rbase ^ (((k >> 2) & 15) << 2));
        float4 xa = *(const float4*)&XsT[k * 64 + base0];
        float4 xb = *(const float4*)&XsT[k * 64 + (base0 ^ 4)];
        acc[0] = f4fma(xa.x, w, acc[0]);
        acc[1] = f4fma(xa.y, w, acc[1]);
        acc[2] = f4fma(xa.z, w, acc[2]);
        acc[3] = f4fma(xa.w, w, acc[3]);
        acc[4] = f4fma(xb.x, w, acc[4]);
        acc[5] = f4fma(xb.y, w, acc[5]);
        acc[6] = f4fma(xb.z, w, acc[6]);
        acc[7] = f4fma(xb.w, w, acc[7]);
    }

    #pragma unroll
    for (int r = 0; r < 8; ++r) {
        int row = row0 + rbase + r;
        if (row < n) {
            float sc = dinv[row];
            __half2 ha = __float22half2_rn(make_float2(sc * acc[r].x, sc * acc[r].y));
            __half2 hb = __float22half2_rn(make_float2(sc * acc[r].z, sc * acc[r].w));
            uint2 st;
            st.x = *reinterpret_cast<unsigned int*>(&ha);
            st.y = *reinterpret_cast<unsigned int*>(&hb);
            Y[(size_t)row * D4 + t] = st;
        }
    }
}

// out[i,:] = prelu( dinv[i]*( sum_e XWS[src_e,:] + XWS[i,:] ) + b ), XWS fp16 pre-scaled.
// block (24,16): 24 lanes/node x uint2 (4 fp16); edge loop unrolled x8; fp32 out.
__global__ __launch_bounds__(384) void aggregate_kernel(const uint2* __restrict__ XH,
                                                        const int* __restrict__ csr,
                                                        const int2* __restrict__ rowspan,
                                                        const float* __restrict__ dinv,
                                                        const float4* __restrict__ b4,
                                                        const float4* __restrict__ pa4,
                                                        float4* __restrict__ out4, int n) {
    const int i = blockIdx.x * 16 + threadIdx.y;
    const int t = threadIdx.x;  // 0..23
    if (i >= n) return;
    const int2 be = rowspan[i];
    float4 a = make_float4(0.f, 0.f, 0.f, 0.f);
    int p = be.x;
    const int end = be.y;
    for (; p + 8 <= end; p += 8) {
        int s0 = csr[p + 0];
        int s1 = csr[p + 1];
        int s2 = csr[p + 2];
        int s3 = csr[p + 3];
        int s4 = csr[p + 4];
        int s5 = csr[p + 5];
        int s6 = csr[p + 6];
        int s7 = csr[p + 7];
        uint2 r0 = XH[(size_t)s0 * D4 + t];
        uint2 r1 = XH[(size_t)s1 * D4 + t];
        uint2 r2 = XH[(size_t)s2 * D4 + t];
        uint2 r3 = XH[(size_t)s3 * D4 + t];
        uint2 r4 = XH[(size_t)s4 * D4 + t];
        uint2 r5 = XH[(size_t)s5 * D4 + t];
        uint2 r6 = XH[(size_t)s6 * D4 + t];
        uint2 r7 = XH[(size_t)s7 * D4 + t];
        u2add(r0, a); u2add(r1, a); u2add(r2, a); u2add(r3, a);
        u2add(r4, a); u2add(r5, a); u2add(r6, a); u2add(r7, a);
    }
    if (p + 4 <= end) {
        int s0 = csr[p + 0];
        int s1 = csr[p + 1];
        int s2 = csr[p + 2];
        int s3 = csr[p + 3];
        uint2 r0 = XH[(size_t)s0 * D4 + t];
        uint2 r1 = XH[(size_t)s1 * D4 + t];
        uint2 r2 = XH[(size_t)s2 * D4 + t];
        uint2 r3 = XH[(size_t)s3 * D4 + t];
        u2add(r0, a); u2add(r1, a); u2add(r2, a); u2add(r3, a);
        p += 4;
    }
    for (; p < end; ++p)
        u2add(XH[(size_t)csr[p] * D4 + t], a);
    // self term (pre-scaled row)
    u2add(XH[(size_t)i * D4 + t], a);
    const float di = dinv[i];
    float4 b = b4[t], q = pa4[t];
    float4 v;
    v.x = fmaf(di, a.x, b.x);
    v.y = fmaf(di, a.y, b.y);
    v.z = fmaf(di, a.z, b.z);
    v.w = fmaf(di, a.w, b.w);
    v.x = v.x > 0.f ? v.x : q.x * v.x;
    v.y = v.y > 0.f ? v.y : q.y * v.y;
    v.z = v.z > 0.f ? v.z : q.z * v.z;
    v.w = v.w > 0.f ? v.w : q.w * v.w;
    out4[(size_t)i * D4 + t] = v;
}

extern "C" void kernel_launch(void* const* d_in, const int* in_sizes, int n_in,
                              void* d_out, int out_size, void* d_ws, size_t ws_size,
                              hipStream_t stream) {
    const float* x   = (const float*)d_in[0];
    const int*   ei  = (const int*)d_in[1];
    const float* W1  = (const float*)d_in[2];
    const float* b1  = (const float*)d_in[3];
    const float* W2  = (const float*)d_in[4];
    const float* b2  = (const float*)d_in[5];
    const float* pa  = (const float*)d_in[6];
    const int n = in_sizes[0] / D;
    const int E = in_sizes[1] / 2;
    const int* srcp = ei;
    const int* dstp = ei + E;

    const int nbins = (n + 255) / 256;               // 196
    const int nblk  = (E + 4095) / 4096;             // 196

    char* w = (char*)d_ws;
    int*   cursor  = (int*)w;    w += alignup(256 * 4);
    int*   ebuf    = (int*)w;    w += alignup((size_t)nbins * CAP * 4);
    int*   csr     = (int*)w;    w += alignup((size_t)nbins * CAP * 4);
    float* dinv    = (float*)w;  w += alignup((size_t)n * 4);
    int2*  rowspan = (int2*)w;   w += alignup((size_t)n * 8);
    uint2* xw      = (uint2*)w;  w += alignup((size_t)n * D * 2);  // fp16 pre-scaled rows
    float* out     = (float*)d_out;

    init_kernel<<<1, 256, 0, stream>>>(cursor);
    dist_kernel<<<nblk, 1024, 0, stream>>>(srcp, dstp, E, cursor, ebuf);
    bucketAB_kernel<<<nbins, 256, 0, stream>>>(ebuf, cursor, dinv, rowspan, csr, n);

    dim3 mblk(24, 8);
    const int mgrid = (n + 63) / 64;
    dim3 ablk(24, 16);
    const int agrid = (n + 15) / 16;

    matmul_kernel<<<mgrid, mblk, 0, stream>>>(x, W1, dinv, xw, n);
    aggregate_kernel<<<agrid, ablk, 0, stream>>>(xw, csr, rowspan, dinv,
                                                 (const float4*)b1, (const float4*)pa, (float4*)out, n);
    matmul_kernel<<<mgrid, mblk, 0, stream>>>(out, W2, dinv, xw, n);
    aggregate_kernel<<<agrid, ablk, 0, stream>>>(xw, csr, rowspan, dinv,
                                                 (const float4*)b2, (const float4*)pa, (float4*)out, n);
}